// Round 14
// baseline (191.796 us; speedup 1.0000x reference)
//
#include <hip/hip_runtime.h>

#define KK 25
// fixed-point scale for packed message accumulation: 2^28
#define FP_SCALE 268435456.0f
#define FP_INV   (1.0f / 268435456.0f)

#define TPB 256
#define EPT 8
#define EPB (TPB * EPT)     // 2048 edges per phase-1 block
#define WSHIFT 10
#define WNODE 1024          // nodes per bin
#define MAXBINS 256         // scan width (>= nbins)
#define CAP 36864           // bucket capacity; mean 32768, +22 sigma

typedef unsigned long long u64;
typedef unsigned u32x4 __attribute__((ext_vector_type(4)));

__global__ void zero_counts(unsigned* __restrict__ p, int n) {
    int i = blockIdx.x * blockDim.x + threadIdx.x;
    if (i < n) p[i] = 0u;
}

// agent-scope 8B load: bypasses (non-coherent) L1, served by L2 directly.
__device__ __forceinline__ float2 ldg_l2(const float2* p) {
    u64 raw = __hip_atomic_load((const u64*)p, __ATOMIC_RELAXED,
                                __HIP_MEMORY_SCOPE_AGENT);
    union { u64 u; float2 f; } cv;
    cv.u = raw;
    return cv.f;
}

// ---------------------------------------------------------------------------
// PHASE 1 v8 (R13 structure, EPT 8): 3126 blocks (~3 dispatch generations at
// ~8 blocks/CU) instead of 1563 (~1 generation) — backfill the tail.
//   pass A: ONE LDS atomic/edge; return value IS the within-bin rank.
//           pk packs bin(8b) | rank(12b, <2048) | node(10b).
//   scan:   shuffle-based; joff[b] = gbase[b] - start[b].
//   pass B: 8-deep L2-direct gather batch; pos = start+rank.
//   flush:  lane-contiguous copy, O(1) bin via bin_map.
// Entry (u32) = msg quantized to top-22 fp32 bits | 10-bit node-within-bin.
// ---------------------------------------------------------------------------
__global__ __launch_bounds__(TPB, 8) void phase1(
    const float* __restrict__ x,      // [N,2]
    const float* __restrict__ w,      // [KK,2]
    const int* __restrict__ row,
    const int* __restrict__ col,
    const float* __restrict__ pseudo, // [E]
    unsigned* __restrict__ bucket,    // [nbins, CAP] u32
    unsigned* __restrict__ gcount,    // [nbins]
    int n_edges)
{
    __shared__ float4  wq[32];               // wq[i] = (w0a,w0b,w1a,w1b)
    __shared__ unsigned bin_cnt[MAXBINS];    // histogram (pass A ranks)
    __shared__ unsigned bin_start[MAXBINS];  // block-local exclusive prefix
    __shared__ unsigned joff[MAXBINS];       // gbase - start (mod 2^32)
    __shared__ unsigned wtot[4];
    __shared__ unsigned stage[EPB];          // 8 KB
    __shared__ unsigned char bin_map[EPB];   // 2 KB

    const int tid = threadIdx.x;
    if (tid < KK) {
        int i1 = min(tid + 1, KK - 1);
        wq[tid] = make_float4(w[2 * tid], w[2 * tid + 1],
                              w[2 * i1],  w[2 * i1 + 1]);
    }
    bin_cnt[tid] = 0u;
    __syncthreads();

    const long long base = (long long)blockIdx.x * EPB;
    const bool full = (base + EPB) <= (long long)n_edges;
    const int nloc = full ? EPB
                          : (int)(((long long)n_edges - base) > 0
                                      ? ((long long)n_edges - base) : 0LL);

    // pass A: rows (vectorized), ONE atomic per edge -> histogram + rank
    unsigned pk[EPT];
    if (full) {
        const int4* r4 = (const int4*)&row[base + (long long)tid * EPT];
        int rloc[EPT];
        #pragma unroll
        for (int q = 0; q < EPT / 4; ++q) {
            int4 rr = r4[q];
            rloc[4 * q + 0] = rr.x; rloc[4 * q + 1] = rr.y;
            rloc[4 * q + 2] = rr.z; rloc[4 * q + 3] = rr.w;
        }
        #pragma unroll
        for (int k = 0; k < EPT; ++k) {
            int r = rloc[k];
            int bin = r >> WSHIFT;
            unsigned rank = atomicAdd(&bin_cnt[bin], 1u);   // rank < 2048
            pk[k] = ((unsigned)bin << 22) | (rank << 10)
                  | (unsigned)(r & (WNODE - 1));
        }
    } else {
        for (int k = 0; k < EPT; ++k) {
            int i = tid * EPT + k;
            if (i < nloc) {
                int r = row[base + i];
                int bin = r >> WSHIFT;
                unsigned rank = atomicAdd(&bin_cnt[bin], 1u);
                pk[k] = ((unsigned)bin << 22) | (rank << 10)
                      | (unsigned)(r & (WNODE - 1));
            } else pk[k] = 0xFFFFFFFFu;
        }
    }
    __syncthreads();

    // shuffle-based exclusive scan over 256 bins (4 waves of 64)
    {
        unsigned v = bin_cnt[tid];
        unsigned incl = v;
        #pragma unroll
        for (int d = 1; d < 64; d <<= 1) {
            unsigned t = __shfl_up(incl, d, 64);
            if ((tid & 63) >= d) incl += t;
        }
        if ((tid & 63) == 63) wtot[tid >> 6] = incl;
        __syncthreads();
        unsigned off = 0;
        const int wv = tid >> 6;
        #pragma unroll
        for (int ww = 0; ww < 4; ++ww)
            if (ww < wv) off += wtot[ww];
        unsigned st = off + incl - v;
        bin_start[tid] = st;
        unsigned gb = v ? atomicAdd(&gcount[tid], v) : 0u;
        joff[tid] = gb - st;                 // mod-2^32 arithmetic is fine
    }
    __syncthreads();

    // pass B: ONE 8-deep L2-direct gather batch per thread (EPT == 8)
    const float2* __restrict__ x2 = (const float2*)x;
    if (full) {
        const int4*   c4 = (const int4*)&col[base + (long long)tid * EPT];
        const float4* p4 = (const float4*)&pseudo[base + (long long)tid * EPT];
        int4   cc0 = c4[0], cc1 = c4[1];
        float4 pp0 = p4[0], pp1 = p4[1];
        float2 xj[8];
        xj[0] = ldg_l2(&x2[cc0.x]); xj[1] = ldg_l2(&x2[cc0.y]);
        xj[2] = ldg_l2(&x2[cc0.z]); xj[3] = ldg_l2(&x2[cc0.w]);
        xj[4] = ldg_l2(&x2[cc1.x]); xj[5] = ldg_l2(&x2[cc1.y]);
        xj[6] = ldg_l2(&x2[cc1.z]); xj[7] = ldg_l2(&x2[cc1.w]);
        float pa[8] = {pp0.x, pp0.y, pp0.z, pp0.w,
                       pp1.x, pp1.y, pp1.z, pp1.w};
        #pragma unroll
        for (int j = 0; j < 8; ++j) {
            unsigned p = pk[j];
            float vv = pa[j] * (float)(KK - 1);   // in [0,24)
            int   i0 = (int)vv;                   // == floor
            float fr = vv - (float)i0;
            float4 qw = wq[i0];
            float wa = qw.x + fr * (qw.z - qw.x);
            float wb = qw.y + fr * (qw.w - qw.y);
            float msg = xj[j].x * wa + xj[j].y * wb;
            unsigned ub = (__float_as_uint(msg) + 0x200u) & 0xFFFFFC00u;
            unsigned bin = p >> 22;
            unsigned pos = bin_start[bin] + ((p >> 10) & 0xFFFu);
            stage[pos] = ub | (p & (WNODE - 1));
            bin_map[pos] = (unsigned char)bin;
        }
    } else {
        for (int k = 0; k < EPT; ++k) {
            int i = tid * EPT + k;
            if (i < nloc) {
                unsigned p = pk[k];
                long long e = base + i;
                int c = col[e];
                float ps = pseudo[e];
                float vv = ps * (float)(KK - 1);
                int   i0 = (int)vv;
                float fr = vv - (float)i0;
                float4 qw = wq[i0];
                float2 xj = ldg_l2(&x2[c]);
                float wa = qw.x + fr * (qw.z - qw.x);
                float wb = qw.y + fr * (qw.w - qw.y);
                float msg = xj.x * wa + xj.y * wb;
                unsigned ub = (__float_as_uint(msg) + 0x200u) & 0xFFFFFC00u;
                unsigned bin = p >> 22;
                unsigned pos = bin_start[bin] + ((p >> 10) & 0xFFFu);
                stage[pos] = ub | (p & (WNODE - 1));
                bin_map[pos] = (unsigned char)bin;
            }
        }
    }
    __syncthreads();

    // flush: lane-contiguous, O(1) bin map; coalesced within runs
    for (int i = tid; i < nloc; i += TPB) {
        unsigned entry = stage[i];
        unsigned b = bin_map[i];
        unsigned g = joff[b] + (unsigned)i;       // bucket-local index
        if (g < CAP) bucket[(size_t)b * CAP + g] = entry;
    }
}

// ---------------------------------------------------------------------------
// PHASE 2 v2: one block (1024 threads) per bin; 8-DEEP batched uint4 loads
// (8 independent loads in flight before first use — MLP fix), LDS packed-u64
// accumulation (fire-and-forget atomics), fused finalize.
// ---------------------------------------------------------------------------
__global__ __launch_bounds__(1024) void phase2(
    const unsigned* __restrict__ bucket,
    const unsigned* __restrict__ gcount,
    float* __restrict__ out, int n_nodes)
{
    __shared__ u64 acc[WNODE];   // 8 KB
    const int tid = threadIdx.x;
    const int bin = blockIdx.x;

    acc[tid] = 0ULL;
    __syncthreads();

    unsigned cnt = gcount[bin];
    if (cnt > CAP) cnt = CAP;
    const unsigned* __restrict__ bb = bucket + (size_t)bin * CAP;

    const unsigned nvec = cnt >> 2;
    const u32x4* __restrict__ b4 = (const u32x4*)bb;

    for (unsigned ibase = tid; ibase < nvec; ibase += 8192) {
        u32x4 v[8];
        #pragma unroll
        for (int d = 0; d < 8; ++d) {
            unsigned ii = ibase + (unsigned)d * 1024u;
            if (ii < nvec) v[d] = b4[ii];      // 8 independent loads in flight
        }
        #pragma unroll
        for (int d = 0; d < 8; ++d) {
            unsigned ii = ibase + (unsigned)d * 1024u;
            if (ii < nvec) {
                #pragma unroll
                for (int j = 0; j < 4; ++j) {
                    unsigned e = v[d][j];
                    float msg = __uint_as_float(e & 0xFFFFFC00u);
                    long long fx = (long long)llrintf(msg * FP_SCALE);
                    atomicAdd(&acc[e & (WNODE - 1)], ((u64)fx << 16) | 1ULL);
                }
            }
        }
    }
    for (unsigned i = (nvec << 2) + tid; i < cnt; i += 1024) {
        unsigned e = bb[i];
        float msg = __uint_as_float(e & 0xFFFFFC00u);
        long long fx = (long long)llrintf(msg * FP_SCALE);
        atomicAdd(&acc[e & (WNODE - 1)], ((u64)fx << 16) | 1ULL);
    }
    __syncthreads();

    const int node = (bin << WSHIFT) + tid;
    if (node < n_nodes) {
        u64 t = acc[tid];
        int count = (int)(t & 0xFFFFULL);
        long long sf = ((long long)t) >> 16;   // arithmetic shift
        float sum = (float)sf * FP_INV;
        out[node] = sum / (float)max(count, 1);
    }
}

// ---------------------------------------------------------------------------
// fallback path (ws too small): single-copy packed device atomics (R3)
// ---------------------------------------------------------------------------
__global__ void zero_acc(u64* __restrict__ p, int n) {
    int i = blockIdx.x * blockDim.x + threadIdx.x;
    if (i < n) p[i] = 0ULL;
}

__global__ void edge_kernel_flat(const float* __restrict__ x,
                                 const float* __restrict__ w,
                                 const int* __restrict__ row,
                                 const int* __restrict__ col,
                                 const float* __restrict__ pseudo,
                                 u64* __restrict__ acc,
                                 int n_edges) {
    __shared__ float wsm[KK * 2];
    if (threadIdx.x < KK * 2) wsm[threadIdx.x] = w[threadIdx.x];
    __syncthreads();

    const float2* __restrict__ x2 = (const float2*)x;
    int e = blockIdx.x * blockDim.x + threadIdx.x;
    if (e >= n_edges) return;

    int r = row[e];
    int c = col[e];
    float p = pseudo[e];
    float vv = p * (float)(KK - 1);
    float lo = floorf(vv);
    float fr = vv - lo;
    int i0 = min(max((int)lo, 0), KK - 1);
    int i1 = min(i0 + 1, KK - 1);
    float2 xj = x2[c];
    float m0 = xj.x * wsm[2 * i0] + xj.y * wsm[2 * i0 + 1];
    float m1 = xj.x * wsm[2 * i1] + xj.y * wsm[2 * i1 + 1];
    float msg = (1.0f - fr) * m0 + fr * m1;

    long long fx = (long long)llrintf(msg * FP_SCALE);
    atomicAdd(&acc[r], ((u64)fx << 16) + 1ULL);
}

__global__ void finalize_flat(const u64* __restrict__ acc,
                              float* __restrict__ out, int n) {
    int i = blockIdx.x * blockDim.x + threadIdx.x;
    if (i >= n) return;
    u64 t = acc[i];
    int count = (int)(t & 0xFFFFULL);
    long long sf = ((long long)t) >> 16;
    float sum = (float)sf * FP_INV;
    out[i] = sum / (float)max(count, 1);
}

extern "C" void kernel_launch(void* const* d_in, const int* in_sizes, int n_in,
                              void* d_out, int out_size, void* d_ws, size_t ws_size,
                              hipStream_t stream) {
    const float* x      = (const float*)d_in[0];   // 200000*2
    const float* w      = (const float*)d_in[1];   // 25*2*1
    const int*   edges  = (const int*)d_in[2];     // 2*E (int32 on device)
    const float* pseudo = (const float*)d_in[3];   // E

    const int n_edges = in_sizes[3];               // 6400000
    const int n_nodes = out_size;                  // 200000

    const int* row = edges;
    const int* col = edges + n_edges;

    const int nbins = (n_nodes + WNODE - 1) >> WSHIFT;   // 196
    const size_t need = 4096 + (size_t)nbins * CAP * sizeof(unsigned);

    if (nbins <= MAXBINS && ws_size >= need) {
        unsigned* gcount = (unsigned*)d_ws;
        unsigned* bucket = (unsigned*)((char*)d_ws + 4096);

        zero_counts<<<1, MAXBINS, 0, stream>>>(gcount, MAXBINS);

        int blocks = (n_edges + EPB - 1) / EPB;    // 3126
        phase1<<<blocks, TPB, 0, stream>>>(x, w, row, col, pseudo,
                                           bucket, gcount, n_edges);

        phase2<<<nbins, 1024, 0, stream>>>(bucket, gcount,
                                           (float*)d_out, n_nodes);
    } else {
        u64* acc = (u64*)d_ws;
        zero_acc<<<(n_nodes + 255) / 256, 256, 0, stream>>>(acc, n_nodes);
        int blocks = (n_edges + 255) / 256;
        edge_kernel_flat<<<blocks, 256, 0, stream>>>(x, w, row, col, pseudo,
                                                     acc, n_edges);
        finalize_flat<<<(n_nodes + 255) / 256, 256, 0, stream>>>(acc,
                                                                 (float*)d_out,
                                                                 n_nodes);
    }
}

// Round 15
// 159.945 us; speedup vs baseline: 1.1991x; 1.1991x over previous
//
#include <hip/hip_runtime.h>

#define KK 25
// fixed-point scale for packed message accumulation: 2^28
#define FP_SCALE 268435456.0f
#define FP_INV   (1.0f / 268435456.0f)

#define TPB 256
#define EPT 16
#define EPB (TPB * EPT)     // 4096 edges per phase-1 block
#define WSHIFT 10
#define WNODE 1024          // nodes per bin
#define MAXBINS 256         // scan width (>= nbins)
#define CAP 36864           // bucket capacity; mean 32768, +22 sigma

typedef unsigned long long u64;
typedef unsigned u32x4 __attribute__((ext_vector_type(4)));

__global__ void zero_counts(unsigned* __restrict__ p, int n) {
    int i = blockIdx.x * blockDim.x + threadIdx.x;
    if (i < n) p[i] = 0u;
}

// agent-scope 8B load: bypasses (non-coherent) L1, served by L2 directly.
__device__ __forceinline__ float2 ldg_l2(const float2* p) {
    u64 raw = __hip_atomic_load((const u64*)p, __ATOMIC_RELAXED,
                                __HIP_MEMORY_SCOPE_AGENT);
    union { u64 u; float2 f; } cv;
    cv.u = raw;
    return cv.f;
}

// ---------------------------------------------------------------------------
// PHASE 1 v9: FUSED pass A (gathers hoisted before the scan barrier).
//   pass A: load row+col+pseudo, issue L2-direct gathers IMMEDIATELY
//           (overlapped with the per-edge LDS rank atomic), compute the
//           final entry (msg|node) into registers. binrank = bin<<12|rank.
//   scan:   shuffle-based.
//   pass B: two LDS writes per edge (stage[pos], bin_map[pos]) — no memory
//           latency after the barrier.
//   flush:  lane-contiguous copy, O(1) bin via bin_map.
// Entry (u32) = msg quantized to top-22 fp32 bits | 10-bit node-within-bin.
// ---------------------------------------------------------------------------
__global__ __launch_bounds__(TPB, 6) void phase1(
    const float* __restrict__ x,      // [N,2]
    const float* __restrict__ w,      // [KK,2]
    const int* __restrict__ row,
    const int* __restrict__ col,
    const float* __restrict__ pseudo, // [E]
    unsigned* __restrict__ bucket,    // [nbins, CAP] u32
    unsigned* __restrict__ gcount,    // [nbins]
    int n_edges)
{
    __shared__ float4  wq[32];               // wq[i] = (w0a,w0b,w1a,w1b)
    __shared__ unsigned bin_cnt[MAXBINS];    // histogram (pass A ranks)
    __shared__ unsigned bin_start[MAXBINS];  // block-local exclusive prefix
    __shared__ unsigned joff[MAXBINS];       // gbase - start (mod 2^32)
    __shared__ unsigned wtot[4];
    __shared__ unsigned stage[EPB];          // 16 KB
    __shared__ unsigned char bin_map[EPB];   // 4 KB

    const int tid = threadIdx.x;
    if (tid < KK) {
        int i1 = min(tid + 1, KK - 1);
        wq[tid] = make_float4(w[2 * tid], w[2 * tid + 1],
                              w[2 * i1],  w[2 * i1 + 1]);
    }
    bin_cnt[tid] = 0u;
    __syncthreads();

    const long long base = (long long)blockIdx.x * EPB;
    const bool full = (base + EPB) <= (long long)n_edges;
    const int nloc = full ? EPB
                          : (int)(((long long)n_edges - base) > 0
                                      ? ((long long)n_edges - base) : 0LL);

    // pass A (fused): stream loads + gathers + rank atomics + msg compute
    unsigned entry[EPT];    // final bucket entry (msg | node)
    unsigned binrank[EPT];  // bin(8b)<<12 | rank(12b)
    const float2* __restrict__ x2 = (const float2*)x;
    if (full) {
        const int4*   r4 = (const int4*)&row[base + (long long)tid * EPT];
        const int4*   c4 = (const int4*)&col[base + (long long)tid * EPT];
        const float4* p4 = (const float4*)&pseudo[base + (long long)tid * EPT];
        #pragma unroll
        for (int h = 0; h < 2; ++h) {               // two batches of 8
            int4   rr0 = r4[2 * h], rr1 = r4[2 * h + 1];
            int4   cc0 = c4[2 * h], cc1 = c4[2 * h + 1];
            float4 pp0 = p4[2 * h], pp1 = p4[2 * h + 1];
            // issue all 8 gathers first (L2-direct, ~200cyc) ...
            float2 xj[8];
            xj[0] = ldg_l2(&x2[cc0.x]); xj[1] = ldg_l2(&x2[cc0.y]);
            xj[2] = ldg_l2(&x2[cc0.z]); xj[3] = ldg_l2(&x2[cc0.w]);
            xj[4] = ldg_l2(&x2[cc1.x]); xj[5] = ldg_l2(&x2[cc1.y]);
            xj[6] = ldg_l2(&x2[cc1.z]); xj[7] = ldg_l2(&x2[cc1.w]);
            int   ra[8] = {rr0.x, rr0.y, rr0.z, rr0.w,
                           rr1.x, rr1.y, rr1.z, rr1.w};
            float pa[8] = {pp0.x, pp0.y, pp0.z, pp0.w,
                           pp1.x, pp1.y, pp1.z, pp1.w};
            // ... rank atomics (LDS pipe) overlap the gather latency ...
            unsigned rk[8];
            #pragma unroll
            for (int j = 0; j < 8; ++j) {
                int bin = ra[j] >> WSHIFT;
                rk[j] = atomicAdd(&bin_cnt[bin], 1u);       // rank < 4096
            }
            // ... then consume gathers into final entries
            #pragma unroll
            for (int j = 0; j < 8; ++j) {
                int k = 8 * h + j;
                float vv = pa[j] * (float)(KK - 1);   // in [0,24)
                int   i0 = (int)vv;                   // == floor
                float fr = vv - (float)i0;
                float4 qw = wq[i0];
                float wa = qw.x + fr * (qw.z - qw.x);
                float wb = qw.y + fr * (qw.w - qw.y);
                float msg = xj[j].x * wa + xj[j].y * wb;
                unsigned ub = (__float_as_uint(msg) + 0x200u) & 0xFFFFFC00u;
                entry[k]   = ub | (unsigned)(ra[j] & (WNODE - 1));
                binrank[k] = ((unsigned)(ra[j] >> WSHIFT) << 12) | rk[j];
            }
        }
    } else {
        for (int k = 0; k < EPT; ++k) {
            int i = tid * EPT + k;
            if (i < nloc) {
                long long e = base + i;
                int r = row[e];
                int c = col[e];
                float ps = pseudo[e];
                int bin = r >> WSHIFT;
                unsigned rank = atomicAdd(&bin_cnt[bin], 1u);
                float vv = ps * (float)(KK - 1);
                int   i0 = (int)vv;
                float fr = vv - (float)i0;
                float4 qw = wq[i0];
                float2 xj = ldg_l2(&x2[c]);
                float wa = qw.x + fr * (qw.z - qw.x);
                float wb = qw.y + fr * (qw.w - qw.y);
                float msg = xj.x * wa + xj.y * wb;
                unsigned ub = (__float_as_uint(msg) + 0x200u) & 0xFFFFFC00u;
                entry[k]   = ub | (unsigned)(r & (WNODE - 1));
                binrank[k] = ((unsigned)bin << 12) | rank;
            } else {
                binrank[k] = 0xFFFFFFFFu;
            }
        }
    }
    __syncthreads();

    // shuffle-based exclusive scan over 256 bins (4 waves of 64)
    {
        unsigned v = bin_cnt[tid];
        unsigned incl = v;
        #pragma unroll
        for (int d = 1; d < 64; d <<= 1) {
            unsigned t = __shfl_up(incl, d, 64);
            if ((tid & 63) >= d) incl += t;
        }
        if ((tid & 63) == 63) wtot[tid >> 6] = incl;
        __syncthreads();
        unsigned off = 0;
        const int wv = tid >> 6;
        #pragma unroll
        for (int ww = 0; ww < 4; ++ww)
            if (ww < wv) off += wtot[ww];
        unsigned st = off + incl - v;
        bin_start[tid] = st;
        unsigned gb = v ? atomicAdd(&gcount[tid], v) : 0u;
        joff[tid] = gb - st;                 // mod-2^32 arithmetic is fine
    }
    __syncthreads();

    // pass B: pure LDS writes — entries already in registers
    if (full) {
        #pragma unroll
        for (int k = 0; k < EPT; ++k) {
            unsigned br  = binrank[k];
            unsigned bin = br >> 12;
            unsigned pos = bin_start[bin] + (br & 0xFFFu);
            stage[pos] = entry[k];
            bin_map[pos] = (unsigned char)bin;
        }
    } else {
        for (int k = 0; k < EPT; ++k) {
            unsigned br = binrank[k];
            if (br != 0xFFFFFFFFu) {
                unsigned bin = br >> 12;
                unsigned pos = bin_start[bin] + (br & 0xFFFu);
                stage[pos] = entry[k];
                bin_map[pos] = (unsigned char)bin;
            }
        }
    }
    __syncthreads();

    // flush: lane-contiguous, O(1) bin map; coalesced within runs
    for (int i = tid; i < nloc; i += TPB) {
        unsigned e = stage[i];
        unsigned b = bin_map[i];
        unsigned g = joff[b] + (unsigned)i;       // bucket-local index
        if (g < CAP) bucket[(size_t)b * CAP + g] = e;
    }
}

// ---------------------------------------------------------------------------
// PHASE 2 (R13 verbatim): one block (1024 threads) per bin. uint4 streaming
// reads, LDS packed-u64 accumulation, fused finalize (one node per thread).
// ---------------------------------------------------------------------------
__global__ __launch_bounds__(1024) void phase2(
    const unsigned* __restrict__ bucket,
    const unsigned* __restrict__ gcount,
    float* __restrict__ out, int n_nodes)
{
    __shared__ u64 acc[WNODE];   // 8 KB
    const int tid = threadIdx.x;
    const int bin = blockIdx.x;

    acc[tid] = 0ULL;
    __syncthreads();

    unsigned cnt = gcount[bin];
    if (cnt > CAP) cnt = CAP;
    const unsigned* __restrict__ bb = bucket + (size_t)bin * CAP;

    const unsigned nvec = cnt >> 2;
    const uint4* __restrict__ b4 = (const uint4*)bb;
    for (unsigned i = tid; i < nvec; i += 1024) {
        uint4 e4 = b4[i];
        unsigned ee[4] = {e4.x, e4.y, e4.z, e4.w};
        #pragma unroll
        for (int j = 0; j < 4; ++j) {
            unsigned e = ee[j];
            float msg = __uint_as_float(e & 0xFFFFFC00u);
            long long fx = (long long)llrintf(msg * FP_SCALE);
            atomicAdd(&acc[e & (WNODE - 1)], ((u64)fx << 16) | 1ULL);
        }
    }
    for (unsigned i = (nvec << 2) + tid; i < cnt; i += 1024) {
        unsigned e = bb[i];
        float msg = __uint_as_float(e & 0xFFFFFC00u);
        long long fx = (long long)llrintf(msg * FP_SCALE);
        atomicAdd(&acc[e & (WNODE - 1)], ((u64)fx << 16) | 1ULL);
    }
    __syncthreads();

    const int node = (bin << WSHIFT) + tid;
    if (node < n_nodes) {
        u64 t = acc[tid];
        int count = (int)(t & 0xFFFFULL);
        long long sf = ((long long)t) >> 16;   // arithmetic shift
        float sum = (float)sf * FP_INV;
        out[node] = sum / (float)max(count, 1);
    }
}

// ---------------------------------------------------------------------------
// fallback path (ws too small): single-copy packed device atomics (R3)
// ---------------------------------------------------------------------------
__global__ void zero_acc(u64* __restrict__ p, int n) {
    int i = blockIdx.x * blockDim.x + threadIdx.x;
    if (i < n) p[i] = 0ULL;
}

__global__ void edge_kernel_flat(const float* __restrict__ x,
                                 const float* __restrict__ w,
                                 const int* __restrict__ row,
                                 const int* __restrict__ col,
                                 const float* __restrict__ pseudo,
                                 u64* __restrict__ acc,
                                 int n_edges) {
    __shared__ float wsm[KK * 2];
    if (threadIdx.x < KK * 2) wsm[threadIdx.x] = w[threadIdx.x];
    __syncthreads();

    const float2* __restrict__ x2 = (const float2*)x;
    int e = blockIdx.x * blockDim.x + threadIdx.x;
    if (e >= n_edges) return;

    int r = row[e];
    int c = col[e];
    float p = pseudo[e];
    float vv = p * (float)(KK - 1);
    float lo = floorf(vv);
    float fr = vv - lo;
    int i0 = min(max((int)lo, 0), KK - 1);
    int i1 = min(i0 + 1, KK - 1);
    float2 xj = x2[c];
    float m0 = xj.x * wsm[2 * i0] + xj.y * wsm[2 * i0 + 1];
    float m1 = xj.x * wsm[2 * i1] + xj.y * wsm[2 * i1 + 1];
    float msg = (1.0f - fr) * m0 + fr * m1;

    long long fx = (long long)llrintf(msg * FP_SCALE);
    atomicAdd(&acc[r], ((u64)fx << 16) + 1ULL);
}

__global__ void finalize_flat(const u64* __restrict__ acc,
                              float* __restrict__ out, int n) {
    int i = blockIdx.x * blockDim.x + threadIdx.x;
    if (i >= n) return;
    u64 t = acc[i];
    int count = (int)(t & 0xFFFFULL);
    long long sf = ((long long)t) >> 16;
    float sum = (float)sf * FP_INV;
    out[i] = sum / (float)max(count, 1);
}

extern "C" void kernel_launch(void* const* d_in, const int* in_sizes, int n_in,
                              void* d_out, int out_size, void* d_ws, size_t ws_size,
                              hipStream_t stream) {
    const float* x      = (const float*)d_in[0];   // 200000*2
    const float* w      = (const float*)d_in[1];   // 25*2*1
    const int*   edges  = (const int*)d_in[2];     // 2*E (int32 on device)
    const float* pseudo = (const float*)d_in[3];   // E

    const int n_edges = in_sizes[3];               // 6400000
    const int n_nodes = out_size;                  // 200000

    const int* row = edges;
    const int* col = edges + n_edges;

    const int nbins = (n_nodes + WNODE - 1) >> WSHIFT;   // 196
    const size_t need = 4096 + (size_t)nbins * CAP * sizeof(unsigned);

    if (nbins <= MAXBINS && ws_size >= need) {
        unsigned* gcount = (unsigned*)d_ws;
        unsigned* bucket = (unsigned*)((char*)d_ws + 4096);

        zero_counts<<<1, MAXBINS, 0, stream>>>(gcount, MAXBINS);

        int blocks = (n_edges + EPB - 1) / EPB;    // 1563
        phase1<<<blocks, TPB, 0, stream>>>(x, w, row, col, pseudo,
                                           bucket, gcount, n_edges);

        phase2<<<nbins, 1024, 0, stream>>>(bucket, gcount,
                                           (float*)d_out, n_nodes);
    } else {
        u64* acc = (u64*)d_ws;
        zero_acc<<<(n_nodes + 255) / 256, 256, 0, stream>>>(acc, n_nodes);
        int blocks = (n_edges + 255) / 256;
        edge_kernel_flat<<<blocks, 256, 0, stream>>>(x, w, row, col, pseudo,
                                                     acc, n_edges);
        finalize_flat<<<(n_nodes + 255) / 256, 256, 0, stream>>>(acc,
                                                                 (float*)d_out,
                                                                 n_nodes);
    }
}

// Round 16
// 154.917 us; speedup vs baseline: 1.2381x; 1.0325x over previous
//
#include <hip/hip_runtime.h>

#define KK 25
// fixed-point scale for packed message accumulation: 2^28
#define FP_SCALE 268435456.0f
#define FP_INV   (1.0f / 268435456.0f)

#define TPB 256
#define EPT 16
#define EPB (TPB * EPT)     // 4096 edges per phase-1 block
#define WSHIFT 10
#define WNODE 1024          // nodes per bin
#define MAXBINS 256         // scan width (>= nbins)
#define CAP 36864           // bucket capacity; mean 32768, +22 sigma

typedef unsigned long long u64;

__global__ void zero_counts(unsigned* __restrict__ p, int n) {
    int i = blockIdx.x * blockDim.x + threadIdx.x;
    if (i < n) p[i] = 0u;
}

// agent-scope 8B load: bypasses (non-coherent) L1, served by L2 directly.
__device__ __forceinline__ float2 ldg_l2(const float2* p) {
    u64 raw = __hip_atomic_load((const u64*)p, __ATOMIC_RELAXED,
                                __HIP_MEMORY_SCOPE_AGENT);
    union { u64 u; float2 f; } cv;
    cv.u = raw;
    return cv.f;
}

// ---------------------------------------------------------------------------
// PHASE 1 v10: fused pass A with a SINGLE 16-deep gather pipeline.
//   pass A: load ALL streams (row/col/pseudo, 12x16B), issue ALL 16
//           L2-direct gathers, then 16 rank atomics (LDS pipe overlaps the
//           ~200cyc gather latency), then consume into final entries.
//           One serial L2 round-trip per thread instead of two (R15).
//   scan:   shuffle-based.
//   pass B: two LDS writes per edge — no memory latency after the barrier.
//   flush:  lane-contiguous copy, O(1) bin via bin_map.
// Entry (u32) = msg quantized to top-22 fp32 bits | 10-bit node-within-bin.
// ---------------------------------------------------------------------------
__global__ __launch_bounds__(TPB, 4) void phase1(
    const float* __restrict__ x,      // [N,2]
    const float* __restrict__ w,      // [KK,2]
    const int* __restrict__ row,
    const int* __restrict__ col,
    const float* __restrict__ pseudo, // [E]
    unsigned* __restrict__ bucket,    // [nbins, CAP] u32
    unsigned* __restrict__ gcount,    // [nbins]
    int n_edges)
{
    __shared__ float4  wq[32];               // wq[i] = (w0a,w0b,w1a,w1b)
    __shared__ unsigned bin_cnt[MAXBINS];    // histogram (pass A ranks)
    __shared__ unsigned bin_start[MAXBINS];  // block-local exclusive prefix
    __shared__ unsigned joff[MAXBINS];       // gbase - start (mod 2^32)
    __shared__ unsigned wtot[4];
    __shared__ unsigned stage[EPB];          // 16 KB
    __shared__ unsigned char bin_map[EPB];   // 4 KB

    const int tid = threadIdx.x;
    if (tid < KK) {
        int i1 = min(tid + 1, KK - 1);
        wq[tid] = make_float4(w[2 * tid], w[2 * tid + 1],
                              w[2 * i1],  w[2 * i1 + 1]);
    }
    bin_cnt[tid] = 0u;
    __syncthreads();

    const long long base = (long long)blockIdx.x * EPB;
    const bool full = (base + EPB) <= (long long)n_edges;
    const int nloc = full ? EPB
                          : (int)(((long long)n_edges - base) > 0
                                      ? ((long long)n_edges - base) : 0LL);

    // pass A (fused, 16-deep): streams + gathers + rank atomics + compute
    unsigned entry[EPT];    // final bucket entry (msg | node)
    unsigned binrank[EPT];  // bin(8b)<<12 | rank(12b)
    const float2* __restrict__ x2 = (const float2*)x;
    if (full) {
        const int4*   r4 = (const int4*)&row[base + (long long)tid * EPT];
        const int4*   c4 = (const int4*)&col[base + (long long)tid * EPT];
        const float4* p4 = (const float4*)&pseudo[base + (long long)tid * EPT];
        int4   rr[4], cc[4];
        float4 pp[4];
        #pragma unroll
        for (int q = 0; q < 4; ++q) { cc[q] = c4[q]; }
        // issue ALL 16 gathers back-to-back (one L2 round-trip, 16 in flight)
        float2 xj[16];
        #pragma unroll
        for (int q = 0; q < 4; ++q) {
            xj[4 * q + 0] = ldg_l2(&x2[cc[q].x]);
            xj[4 * q + 1] = ldg_l2(&x2[cc[q].y]);
            xj[4 * q + 2] = ldg_l2(&x2[cc[q].z]);
            xj[4 * q + 3] = ldg_l2(&x2[cc[q].w]);
        }
        #pragma unroll
        for (int q = 0; q < 4; ++q) { rr[q] = r4[q]; pp[q] = p4[q]; }
        int   ra[16];
        float pa[16];
        #pragma unroll
        for (int q = 0; q < 4; ++q) {
            ra[4 * q + 0] = rr[q].x; ra[4 * q + 1] = rr[q].y;
            ra[4 * q + 2] = rr[q].z; ra[4 * q + 3] = rr[q].w;
            pa[4 * q + 0] = pp[q].x; pa[4 * q + 1] = pp[q].y;
            pa[4 * q + 2] = pp[q].z; pa[4 * q + 3] = pp[q].w;
        }
        // rank atomics on the LDS pipe overlap the in-flight gathers
        unsigned rk[16];
        #pragma unroll
        for (int k = 0; k < EPT; ++k) {
            int bin = ra[k] >> WSHIFT;
            rk[k] = atomicAdd(&bin_cnt[bin], 1u);       // rank < 4096
        }
        // consume gathers into final entries
        #pragma unroll
        for (int k = 0; k < EPT; ++k) {
            float vv = pa[k] * (float)(KK - 1);   // in [0,24)
            int   i0 = (int)vv;                   // == floor
            float fr = vv - (float)i0;
            float4 qw = wq[i0];
            float wa = qw.x + fr * (qw.z - qw.x);
            float wb = qw.y + fr * (qw.w - qw.y);
            float msg = xj[k].x * wa + xj[k].y * wb;
            unsigned ub = (__float_as_uint(msg) + 0x200u) & 0xFFFFFC00u;
            entry[k]   = ub | (unsigned)(ra[k] & (WNODE - 1));
            binrank[k] = ((unsigned)(ra[k] >> WSHIFT) << 12) | rk[k];
        }
    } else {
        for (int k = 0; k < EPT; ++k) {
            int i = tid * EPT + k;
            if (i < nloc) {
                long long e = base + i;
                int r = row[e];
                int c = col[e];
                float ps = pseudo[e];
                int bin = r >> WSHIFT;
                unsigned rank = atomicAdd(&bin_cnt[bin], 1u);
                float vv = ps * (float)(KK - 1);
                int   i0 = (int)vv;
                float fr = vv - (float)i0;
                float4 qw = wq[i0];
                float2 xj = ldg_l2(&x2[c]);
                float wa = qw.x + fr * (qw.z - qw.x);
                float wb = qw.y + fr * (qw.w - qw.y);
                float msg = xj.x * wa + xj.y * wb;
                unsigned ub = (__float_as_uint(msg) + 0x200u) & 0xFFFFFC00u;
                entry[k]   = ub | (unsigned)(r & (WNODE - 1));
                binrank[k] = ((unsigned)bin << 12) | rank;
            } else {
                binrank[k] = 0xFFFFFFFFu;
            }
        }
    }
    __syncthreads();

    // shuffle-based exclusive scan over 256 bins (4 waves of 64)
    {
        unsigned v = bin_cnt[tid];
        unsigned incl = v;
        #pragma unroll
        for (int d = 1; d < 64; d <<= 1) {
            unsigned t = __shfl_up(incl, d, 64);
            if ((tid & 63) >= d) incl += t;
        }
        if ((tid & 63) == 63) wtot[tid >> 6] = incl;
        __syncthreads();
        unsigned off = 0;
        const int wv = tid >> 6;
        #pragma unroll
        for (int ww = 0; ww < 4; ++ww)
            if (ww < wv) off += wtot[ww];
        unsigned st = off + incl - v;
        bin_start[tid] = st;
        unsigned gb = v ? atomicAdd(&gcount[tid], v) : 0u;
        joff[tid] = gb - st;                 // mod-2^32 arithmetic is fine
    }
    __syncthreads();

    // pass B: pure LDS writes — entries already in registers
    if (full) {
        #pragma unroll
        for (int k = 0; k < EPT; ++k) {
            unsigned br  = binrank[k];
            unsigned bin = br >> 12;
            unsigned pos = bin_start[bin] + (br & 0xFFFu);
            stage[pos] = entry[k];
            bin_map[pos] = (unsigned char)bin;
        }
    } else {
        for (int k = 0; k < EPT; ++k) {
            unsigned br = binrank[k];
            if (br != 0xFFFFFFFFu) {
                unsigned bin = br >> 12;
                unsigned pos = bin_start[bin] + (br & 0xFFFu);
                stage[pos] = entry[k];
                bin_map[pos] = (unsigned char)bin;
            }
        }
    }
    __syncthreads();

    // flush: lane-contiguous, O(1) bin map; coalesced within runs
    for (int i = tid; i < nloc; i += TPB) {
        unsigned e = stage[i];
        unsigned b = bin_map[i];
        unsigned g = joff[b] + (unsigned)i;       // bucket-local index
        if (g < CAP) bucket[(size_t)b * CAP + g] = e;
    }
}

// ---------------------------------------------------------------------------
// PHASE 2 (R13 verbatim): one block (1024 threads) per bin. uint4 streaming
// reads, LDS packed-u64 accumulation, fused finalize (one node per thread).
// ---------------------------------------------------------------------------
__global__ __launch_bounds__(1024) void phase2(
    const unsigned* __restrict__ bucket,
    const unsigned* __restrict__ gcount,
    float* __restrict__ out, int n_nodes)
{
    __shared__ u64 acc[WNODE];   // 8 KB
    const int tid = threadIdx.x;
    const int bin = blockIdx.x;

    acc[tid] = 0ULL;
    __syncthreads();

    unsigned cnt = gcount[bin];
    if (cnt > CAP) cnt = CAP;
    const unsigned* __restrict__ bb = bucket + (size_t)bin * CAP;

    const unsigned nvec = cnt >> 2;
    const uint4* __restrict__ b4 = (const uint4*)bb;
    for (unsigned i = tid; i < nvec; i += 1024) {
        uint4 e4 = b4[i];
        unsigned ee[4] = {e4.x, e4.y, e4.z, e4.w};
        #pragma unroll
        for (int j = 0; j < 4; ++j) {
            unsigned e = ee[j];
            float msg = __uint_as_float(e & 0xFFFFFC00u);
            long long fx = (long long)llrintf(msg * FP_SCALE);
            atomicAdd(&acc[e & (WNODE - 1)], ((u64)fx << 16) | 1ULL);
        }
    }
    for (unsigned i = (nvec << 2) + tid; i < cnt; i += 1024) {
        unsigned e = bb[i];
        float msg = __uint_as_float(e & 0xFFFFFC00u);
        long long fx = (long long)llrintf(msg * FP_SCALE);
        atomicAdd(&acc[e & (WNODE - 1)], ((u64)fx << 16) | 1ULL);
    }
    __syncthreads();

    const int node = (bin << WSHIFT) + tid;
    if (node < n_nodes) {
        u64 t = acc[tid];
        int count = (int)(t & 0xFFFFULL);
        long long sf = ((long long)t) >> 16;   // arithmetic shift
        float sum = (float)sf * FP_INV;
        out[node] = sum / (float)max(count, 1);
    }
}

// ---------------------------------------------------------------------------
// fallback path (ws too small): single-copy packed device atomics (R3)
// ---------------------------------------------------------------------------
__global__ void zero_acc(u64* __restrict__ p, int n) {
    int i = blockIdx.x * blockDim.x + threadIdx.x;
    if (i < n) p[i] = 0ULL;
}

__global__ void edge_kernel_flat(const float* __restrict__ x,
                                 const float* __restrict__ w,
                                 const int* __restrict__ row,
                                 const int* __restrict__ col,
                                 const float* __restrict__ pseudo,
                                 u64* __restrict__ acc,
                                 int n_edges) {
    __shared__ float wsm[KK * 2];
    if (threadIdx.x < KK * 2) wsm[threadIdx.x] = w[threadIdx.x];
    __syncthreads();

    const float2* __restrict__ x2 = (const float2*)x;
    int e = blockIdx.x * blockDim.x + threadIdx.x;
    if (e >= n_edges) return;

    int r = row[e];
    int c = col[e];
    float p = pseudo[e];
    float vv = p * (float)(KK - 1);
    float lo = floorf(vv);
    float fr = vv - lo;
    int i0 = min(max((int)lo, 0), KK - 1);
    int i1 = min(i0 + 1, KK - 1);
    float2 xj = x2[c];
    float m0 = xj.x * wsm[2 * i0] + xj.y * wsm[2 * i0 + 1];
    float m1 = xj.x * wsm[2 * i1] + xj.y * wsm[2 * i1 + 1];
    float msg = (1.0f - fr) * m0 + fr * m1;

    long long fx = (long long)llrintf(msg * FP_SCALE);
    atomicAdd(&acc[r], ((u64)fx << 16) + 1ULL);
}

__global__ void finalize_flat(const u64* __restrict__ acc,
                              float* __restrict__ out, int n) {
    int i = blockIdx.x * blockDim.x + threadIdx.x;
    if (i >= n) return;
    u64 t = acc[i];
    int count = (int)(t & 0xFFFFULL);
    long long sf = ((long long)t) >> 16;
    float sum = (float)sf * FP_INV;
    out[i] = sum / (float)max(count, 1);
}

extern "C" void kernel_launch(void* const* d_in, const int* in_sizes, int n_in,
                              void* d_out, int out_size, void* d_ws, size_t ws_size,
                              hipStream_t stream) {
    const float* x      = (const float*)d_in[0];   // 200000*2
    const float* w      = (const float*)d_in[1];   // 25*2*1
    const int*   edges  = (const int*)d_in[2];     // 2*E (int32 on device)
    const float* pseudo = (const float*)d_in[3];   // E

    const int n_edges = in_sizes[3];               // 6400000
    const int n_nodes = out_size;                  // 200000

    const int* row = edges;
    const int* col = edges + n_edges;

    const int nbins = (n_nodes + WNODE - 1) >> WSHIFT;   // 196
    const size_t need = 4096 + (size_t)nbins * CAP * sizeof(unsigned);

    if (nbins <= MAXBINS && ws_size >= need) {
        unsigned* gcount = (unsigned*)d_ws;
        unsigned* bucket = (unsigned*)((char*)d_ws + 4096);

        zero_counts<<<1, MAXBINS, 0, stream>>>(gcount, MAXBINS);

        int blocks = (n_edges + EPB - 1) / EPB;    // 1563
        phase1<<<blocks, TPB, 0, stream>>>(x, w, row, col, pseudo,
                                           bucket, gcount, n_edges);

        phase2<<<nbins, 1024, 0, stream>>>(bucket, gcount,
                                           (float*)d_out, n_nodes);
    } else {
        u64* acc = (u64*)d_ws;
        zero_acc<<<(n_nodes + 255) / 256, 256, 0, stream>>>(acc, n_nodes);
        int blocks = (n_edges + 255) / 256;
        edge_kernel_flat<<<blocks, 256, 0, stream>>>(x, w, row, col, pseudo,
                                                     acc, n_edges);
        finalize_flat<<<(n_nodes + 255) / 256, 256, 0, stream>>>(acc,
                                                                 (float*)d_out,
                                                                 n_nodes);
    }
}